// Round 10
// baseline (74.467 us; speedup 1.0000x reference)
//
#include <hip/hip_runtime.h>

// Problem constants (from reference setup_inputs)
#define N_NODES 50000
#define N_EDGES 600000
#define D_FEAT 128

#define NBLOCKS 586                        // = ceil(150000/256); 4 waves/block
#define NTHREADS (NBLOCKS * 256)           // 150016 (mod 32 == 0 -> gl invariant)
#define NODE_TASKS (N_NODES * 32)          // 1.6M lane-tasks, 32 lanes/node

// Native clang vector types (16B/8B vector ops; HIP_vector_type structs are
// rejected by __builtin_nontemporal_*)
typedef float vfloat4 __attribute__((ext_vector_type(4)));
typedef float vfloat2 __attribute__((ext_vector_type(2)));
typedef int   vint4   __attribute__((ext_vector_type(4)));

#define LOG2E 1.4426950408889634f

__device__ __forceinline__ float fast_sigmoid(float x) {
    return __builtin_amdgcn_rcpf(1.0f + __builtin_amdgcn_exp2f(-x * LOG2E));
}

__device__ __forceinline__ vfloat2 edge_math(float we, vfloat2 ps, vfloat2 qd,
                                             float b0, float b1)
{
    const float l0 = we * (ps.x + qd.x) + b0;
    const float l1 = we * (ps.y + qd.y) + b1;
    const float s0 = fast_sigmoid(l0);
    const float s1 = fast_sigmoid(l1);
    const float o0 = fast_sigmoid(s0 - s1);   // softmax over 2 = sigmoid(diff)
    vfloat2 r; r.x = o0; r.y = 1.0f - o0;
    return r;
}

// ---------------------------------------------------------------------------
// Fused single-dispatch kernel with a lean grid barrier.
//  phase 0: prefetch this thread's 4-edge stream data into registers
//           (in flight under phase 1's h-stream).
//  phase 1: grid-stride node projection (32 lanes/node, 16B/lane h loads,
//           5-shuffle parity reduce, 4B/lane coalesced pq writes).
//  barrier: per-block arrive via atomicAdd(release, agent) + thread-0 spin
//           with s_sleep backoff on acquire loads. 586 blocks = 2344 waves,
//           all co-resident (<< 8192 device capacity) -> deadlock-free.
//           Agent scope gives cross-XCD visibility of pq (r5 lesson: the
//           concept is fine, cg::sync's implementation was the 80us cost).
//  phase 2: per-edge pq gathers (L2-resident after first touch) + activation
//           + NT 16B stores.
// ---------------------------------------------------------------------------
__global__ __launch_bounds__(256) void fused_kernel(
    const vfloat4* __restrict__ h4, // [N_NODES*32]
    const float* __restrict__ w,    // [N_EDGES]
    const int* __restrict__ src,    // [N_EDGES]
    const int* __restrict__ dst,    // [N_EDGES]
    const float* __restrict__ W,    // [256,2]
    const float* __restrict__ b,    // [2]
    float* __restrict__ pqf,        // [N_NODES*4] workspace
    unsigned int* __restrict__ bar, // barrier counter (memset to 0 per call)
    vfloat4* __restrict__ out4)     // [N_EDGES/2]
{
    const int t = blockIdx.x * 256 + threadIdx.x;
    const int gl = threadIdx.x & 31;

    // ---- phase 0: prefetch edge streams (overlap with phase 1)
    vfloat4 wv = {0.f, 0.f, 0.f, 0.f};
    vint4 sv = {0, 0, 0, 0}, dv = {0, 0, 0, 0};
    const bool has_edge = t < (N_EDGES / 4);
    if (has_edge) {
        wv = *reinterpret_cast<const vfloat4*>(w + 4 * t);
        sv = *reinterpret_cast<const vint4*>(src + 4 * t);
        dv = *reinterpret_cast<const vint4*>(dst + 4 * t);
    }

    // ---- W fragments (2 KB, L1-resident); gl invariant across grid-stride
    const vfloat4 wt0 = *reinterpret_cast<const vfloat4*>(W + 8 * gl);
    const vfloat4 wt1 = *reinterpret_cast<const vfloat4*>(W + 8 * gl + 4);
    const vfloat4 wb0 = *reinterpret_cast<const vfloat4*>(W + 256 + 8 * gl);
    const vfloat4 wb1 = *reinterpret_cast<const vfloat4*>(W + 256 + 8 * gl + 4);

    // ---- phase 1: node projection, grid-stride (10-11 iters)
    for (int idx = t; idx < NODE_TASKS; idx += NTHREADS) {
        const vfloat4 hv = h4[idx];

        const float p0 = hv.x * wt0.x + hv.y * wt0.z + hv.z * wt1.x + hv.w * wt1.z;
        const float p1 = hv.x * wt0.y + hv.y * wt0.w + hv.z * wt1.y + hv.w * wt1.w;
        const float q0 = hv.x * wb0.x + hv.y * wb0.z + hv.z * wb1.x + hv.w * wb1.z;
        const float q1 = hv.x * wb0.y + hv.y * wb0.w + hv.z * wb1.y + hv.w * wb1.w;

        // parity-specialized reduce: 5 shuffles
        const bool o1 = gl & 1;
        float v = o1 ? p1 : p0;
        float u = o1 ? p0 : p1;
        v += __shfl_xor(u, 1, 64);
        float x = o1 ? q1 : q0;
        float y = o1 ? q0 : q1;
        x += __shfl_xor(y, 1, 64);

        const bool o2 = gl & 2;
        float z = o2 ? x : v;
        float tt = o2 ? v : x;
        z += __shfl_xor(tt, 2, 64);

        z += __shfl_xor(z, 4, 64);
        z += __shfl_xor(z, 8, 64);
        z += __shfl_xor(z, 16, 64);

        if (gl < 4) pqf[(size_t)(idx >> 5) * 4 + gl] = z;
    }

    // ---- lean grid barrier
    __syncthreads();                      // block's pq stores ordered before arrive
    if (threadIdx.x == 0) {
        __hip_atomic_fetch_add(bar, 1u, __ATOMIC_RELEASE, __HIP_MEMORY_SCOPE_AGENT);
        while (__hip_atomic_load(bar, __ATOMIC_ACQUIRE, __HIP_MEMORY_SCOPE_AGENT)
               < (unsigned int)NBLOCKS) {
            __builtin_amdgcn_s_sleep(4);  // backoff so spinners don't hammer L3
        }
    }
    __syncthreads();                      // release whole block after acquire

    // ---- phase 2: edges (stream data already in registers)
    if (has_edge) {
        const float b0 = b[0], b1 = b[1];

        const vfloat2 ps0 = *reinterpret_cast<const vfloat2*>(pqf + (size_t)sv.x * 4);
        const vfloat2 ps1 = *reinterpret_cast<const vfloat2*>(pqf + (size_t)sv.y * 4);
        const vfloat2 ps2 = *reinterpret_cast<const vfloat2*>(pqf + (size_t)sv.z * 4);
        const vfloat2 ps3 = *reinterpret_cast<const vfloat2*>(pqf + (size_t)sv.w * 4);
        const vfloat2 qd0 = *reinterpret_cast<const vfloat2*>(pqf + (size_t)dv.x * 4 + 2);
        const vfloat2 qd1 = *reinterpret_cast<const vfloat2*>(pqf + (size_t)dv.y * 4 + 2);
        const vfloat2 qd2 = *reinterpret_cast<const vfloat2*>(pqf + (size_t)dv.z * 4 + 2);
        const vfloat2 qd3 = *reinterpret_cast<const vfloat2*>(pqf + (size_t)dv.w * 4 + 2);

        const vfloat2 r0 = edge_math(wv.x, ps0, qd0, b0, b1);
        const vfloat2 r1 = edge_math(wv.y, ps1, qd1, b0, b1);
        const vfloat2 r2 = edge_math(wv.z, ps2, qd2, b0, b1);
        const vfloat2 r3 = edge_math(wv.w, ps3, qd3, b0, b1);

        vfloat4 o0; o0.x = r0.x; o0.y = r0.y; o0.z = r1.x; o0.w = r1.y;
        vfloat4 o1; o1.x = r2.x; o1.y = r2.y; o1.z = r3.x; o1.w = r3.y;
        __builtin_nontemporal_store(o0, &out4[2 * t]);
        __builtin_nontemporal_store(o1, &out4[2 * t + 1]);
    }
}

extern "C" void kernel_launch(void* const* d_in, const int* in_sizes, int n_in,
                              void* d_out, int out_size, void* d_ws, size_t ws_size,
                              hipStream_t stream) {
    const float* h   = (const float*)d_in[0];  // [50000,128]
    const float* w   = (const float*)d_in[1];  // [600000,1]
    const int*   src = (const int*)d_in[2];    // [600000]
    const int*   dst = (const int*)d_in[3];    // [600000]
    const float* W   = (const float*)d_in[4];  // [256,2]
    const float* b   = (const float*)d_in[5];  // [2]

    float* pq = (float*)d_ws;                              // 800 KB pq table
    unsigned int* bar = (unsigned int*)((char*)d_ws + (1u << 20)); // counter @1MiB
    vfloat4* out = (vfloat4*)d_out;
    const vfloat4* h4 = reinterpret_cast<const vfloat4*>(h);

    // zero the barrier counter (capturable memset node, ordered before kernel)
    hipMemsetAsync(bar, 0, sizeof(unsigned int), stream);

    fused_kernel<<<NBLOCKS, 256, 0, stream>>>(h4, w, src, dst, W, b, pq, bar, out);
}

// Round 11
// 22.192 us; speedup vs baseline: 3.3556x; 3.3556x over previous
//
#include <hip/hip_runtime.h>

// Problem constants (from reference setup_inputs)
#define N_NODES 50000
#define N_EDGES 600000
#define D_FEAT 128

// Native clang vector types (16B/8B vector ops; HIP_vector_type structs are
// rejected by __builtin_nontemporal_*)
typedef float vfloat4 __attribute__((ext_vector_type(4)));
typedef float vfloat2 __attribute__((ext_vector_type(2)));
typedef int   vint2   __attribute__((ext_vector_type(2)));

#define LOG2E 1.4426950408889634f

// ---------------------------------------------------------------------------
// Kernel 1: per-node projection, 16 lanes per node (4 nodes per wave).
// Lane gl in [0,16) covers feature cols 8*gl .. 8*gl+7 via TWO independent
// 16B loads (32B/lane). vs the 32-lane version: same bytes, HALF the threads
// (800K vs 1.6M) -> half the total shuffle/issue ops and half the waves to
// ramp. Reduce: 2 pack steps (roles p0,p1,q0,q1 on gl&3) + xor4 + xor8.
// Lanes 0-3 of each 16-group write 4B each (16B coalesced per node).
// Plain cacheable loads: replays keep h L3-resident (r5/r6/r10 evidence).
// ---------------------------------------------------------------------------
__global__ __launch_bounds__(256) void node_proj_kernel(
    const vfloat4* __restrict__ h4, // [N_NODES * 32] (= [N_NODES, 128] f32)
    const float* __restrict__ W,    // [256, 2] row-major
    float* __restrict__ pqf)        // [N_NODES * 4]
{
    const int tid = blockIdx.x * blockDim.x + threadIdx.x;
    const int node = tid >> 4;              // 16 lanes per node
    if (node >= N_NODES) return;
    const int gl = threadIdx.x & 15;        // lane within 16-group

    // two independent 16B loads: cols 8gl..8gl+3 and 8gl+4..8gl+7
    const vfloat4 hv0 = h4[(size_t)node * 32 + 2 * gl];
    const vfloat4 hv1 = h4[(size_t)node * 32 + 2 * gl + 1];

    // W fragments for cols k=8gl..8gl+7: top half floats [16gl..16gl+15],
    // bottom half at +256 floats. 2 KB total -> L1-resident.
    const vfloat4 wt0 = *reinterpret_cast<const vfloat4*>(W + 16 * gl);
    const vfloat4 wt1 = *reinterpret_cast<const vfloat4*>(W + 16 * gl + 4);
    const vfloat4 wt2 = *reinterpret_cast<const vfloat4*>(W + 16 * gl + 8);
    const vfloat4 wt3 = *reinterpret_cast<const vfloat4*>(W + 16 * gl + 12);
    const vfloat4 wb0 = *reinterpret_cast<const vfloat4*>(W + 256 + 16 * gl);
    const vfloat4 wb1 = *reinterpret_cast<const vfloat4*>(W + 256 + 16 * gl + 4);
    const vfloat4 wb2 = *reinterpret_cast<const vfloat4*>(W + 256 + 16 * gl + 8);
    const vfloat4 wb3 = *reinterpret_cast<const vfloat4*>(W + 256 + 16 * gl + 12);

    const float p0 = hv0.x * wt0.x + hv0.y * wt0.z + hv0.z * wt1.x + hv0.w * wt1.z
                   + hv1.x * wt2.x + hv1.y * wt2.z + hv1.z * wt3.x + hv1.w * wt3.z;
    const float p1 = hv0.x * wt0.y + hv0.y * wt0.w + hv0.z * wt1.y + hv0.w * wt1.w
                   + hv1.x * wt2.y + hv1.y * wt2.w + hv1.z * wt3.y + hv1.w * wt3.w;
    const float q0 = hv0.x * wb0.x + hv0.y * wb0.z + hv0.z * wb1.x + hv0.w * wb1.z
                   + hv1.x * wb2.x + hv1.y * wb2.z + hv1.z * wb3.x + hv1.w * wb3.z;
    const float q1 = hv0.x * wb0.y + hv0.y * wb0.w + hv0.z * wb1.y + hv0.w * wb1.w
                   + hv1.x * wb2.y + hv1.y * wb2.w + hv1.z * wb3.y + hv1.w * wb3.w;

    // Step 1 (xor 1): even lanes accumulate p0/q0, odd lanes p1/q1.
    const bool o1 = gl & 1;
    float v = o1 ? p1 : p0;
    float u = o1 ? p0 : p1;
    v += __shfl_xor(u, 1, 64);
    float x = o1 ? q1 : q0;
    float y = o1 ? q0 : q1;
    x += __shfl_xor(y, 1, 64);

    // Step 2 (xor 2): bit1=0 lanes keep P, bit1=1 lanes keep Q.
    const bool o2 = gl & 2;
    float z = o2 ? x : v;
    float t = o2 ? v : x;
    z += __shfl_xor(t, 2, 64);

    // Steps 3-4: lane gl holds component (gl&3); sum across the 16-group.
    z += __shfl_xor(z, 4, 64);
    z += __shfl_xor(z, 8, 64);

    if (gl < 4) pqf[(size_t)node * 4 + gl] = z;
}

// ---------------------------------------------------------------------------
// Kernel 2 (r6 exact, best measured): 2 edges/thread; float2 gathers from
// the L2/L3-resident pq table; softmax(sigmoid(l), axis=1) over 2 classes
// == sigmoid(s0-s1). Transcendentals via raw v_exp_f32 / v_rcp_f32.
// ---------------------------------------------------------------------------
__device__ __forceinline__ float fast_sigmoid(float x) {
    return __builtin_amdgcn_rcpf(1.0f + __builtin_amdgcn_exp2f(-x * LOG2E));
}

__device__ __forceinline__ vfloat2 edge_out(float we, int s, int d,
                                            const float* __restrict__ pq,
                                            float b0, float b1)
{
    // ps needs pq[s*4+0..1] (p of src); qd needs pq[d*4+2..3] (q of dst)
    const vfloat2 ps = *reinterpret_cast<const vfloat2*>(pq + (size_t)s * 4);
    const vfloat2 qd = *reinterpret_cast<const vfloat2*>(pq + (size_t)d * 4 + 2);
    const float l0 = we * (ps.x + qd.x) + b0;
    const float l1 = we * (ps.y + qd.y) + b1;
    const float s0 = fast_sigmoid(l0);
    const float s1 = fast_sigmoid(l1);
    const float o0 = fast_sigmoid(s0 - s1);
    vfloat2 r; r.x = o0; r.y = 1.0f - o0;
    return r;
}

__global__ __launch_bounds__(256) void edge_kernel(
    const float* __restrict__ w,     // [N_EDGES]
    const int* __restrict__ src,     // [N_EDGES]
    const int* __restrict__ dst,     // [N_EDGES]
    const float* __restrict__ pq,    // [N_NODES * 4]
    const float* __restrict__ b,     // [2]
    vfloat4* __restrict__ out4)      // [N_EDGES/2] (= [N_EDGES, 2] f32)
{
    const int t = blockIdx.x * blockDim.x + threadIdx.x;
    if (t >= N_EDGES / 2) return;

    const vfloat2 wv = *reinterpret_cast<const vfloat2*>(w + 2 * t);
    const vint2 sv = *reinterpret_cast<const vint2*>(src + 2 * t);
    const vint2 dv = *reinterpret_cast<const vint2*>(dst + 2 * t);
    const float b0 = b[0], b1 = b[1];

    const vfloat2 r0 = edge_out(wv.x, sv.x, dv.x, pq, b0, b1);
    const vfloat2 r1 = edge_out(wv.y, sv.y, dv.y, pq, b0, b1);

    vfloat4 o; o.x = r0.x; o.y = r0.y; o.z = r1.x; o.w = r1.y;
    out4[t] = o;
}

extern "C" void kernel_launch(void* const* d_in, const int* in_sizes, int n_in,
                              void* d_out, int out_size, void* d_ws, size_t ws_size,
                              hipStream_t stream) {
    const float* h   = (const float*)d_in[0];  // [50000,128]
    const float* w   = (const float*)d_in[1];  // [600000,1]
    const int*   src = (const int*)d_in[2];    // [600000]
    const int*   dst = (const int*)d_in[3];    // [600000]
    const float* W   = (const float*)d_in[4];  // [256,2]
    const float* b   = (const float*)d_in[5];  // [2]

    float* pq = (float*)d_ws;                  // 50000 * 16 B = 800 KB scratch
    vfloat4* out = (vfloat4*)d_out;

    // Kernel 1: 16 lanes/node -> 800000 threads, 3125 blocks of 256
    const int n_blocks1 = (N_NODES * 16 + 255) / 256;
    node_proj_kernel<<<n_blocks1, 256, 0, stream>>>(
        reinterpret_cast<const vfloat4*>(h), W, pq);

    // Kernel 2: 2 edges/thread -> 300000 threads, 1172 blocks of 256
    const int n_blocks2 = (N_EDGES / 2 + 255) / 256;
    edge_kernel<<<n_blocks2, 256, 0, stream>>>(w, src, dst, pq, b, out);
}